// Round 7
// baseline (823.582 us; speedup 1.0000x reference)
//
#include <hip/hip_runtime.h>
#include <hip/hip_bf16.h>
#include <math.h>

typedef __bf16 bf16;
typedef bf16 bf16x8 __attribute__((ext_vector_type(8)));
typedef bf16 bf16x4 __attribute__((ext_vector_type(4)));
typedef float f32x4 __attribute__((ext_vector_type(4)));

#define MFMA16(a, b, c) __builtin_amdgcn_mfma_f32_16x16x32_bf16(a, b, c, 0, 0, 0)

// XOR-swizzle on 16B chunks within a row: breaks power-of-2 row-stride bank aliasing.
__device__ __forceinline__ uint32_t swz(uint32_t base, uint32_t row, uint32_t rs, uint32_t cb) {
    return base + row * rs + (((cb >> 4) ^ (row & 7u)) << 4) + (cb & 15u);
}

// Scratch map (row r = one of 32768 tokens):
//  src  slice r*2048B: [0,1024)=x_bf16 (xcvt; dead after outproj) -> h[1024:1536]
//                      [1024,2048)=x1 bf16 (outproj; read ff1, ff2-residual)
//  dout slice r*2048B: [0,1024)=k, [1024,2048)=v (qkv; dead after attn)
//                      -> h[0:1024] (ff1) -> final f32 out row (ff2, after h consumed)
//  ws: [0,6.3MB)=bf16 weights; [6.3,39.8MB) r*1024B: q (qkv) -> O (attn, same
//      block/cols) -> h[1536:2048] (ff1)

// ---------- weights f32 -> bf16 ----------
__global__ void wcvt_kernel(const float* __restrict__ w0, const float* __restrict__ w1,
                            const float* __restrict__ w2, const float* __restrict__ w3,
                            bf16* __restrict__ o) {
    int i = blockIdx.x * blockDim.x + threadIdx.x;
    int e = i * 4;
    const float* s;
    int off;
    if (e < 786432)       { s = w0; off = e; }
    else if (e < 1048576) { s = w1; off = e - 786432; }
    else if (e < 2097152) { s = w2; off = e - 1048576; }
    else                  { s = w3; off = e - 2097152; }
    float4 v = *(const float4*)(s + off);
    bf16x4 h = { (bf16)v.x, (bf16)v.y, (bf16)v.z, (bf16)v.w };
    *(bf16x4*)(o + e) = h;
}

// ---------- src f32 -> bf16 in place (row-aligned slot; wave per row) ----------
__global__ void xcvt_kernel(float* __restrict__ src) {
    int row = blockIdx.x * 4 + (threadIdx.x >> 6);
    int l = threadIdx.x & 63;
    float* rp = src + (size_t)row * 512 + l * 8;
    float4 v0 = *(const float4*)rp;
    float4 v1 = *(const float4*)(rp + 4);
    asm volatile("s_waitcnt vmcnt(0)" ::: "memory");  // all wave reads before any write
    bf16x8 h = { (bf16)v0.x, (bf16)v0.y, (bf16)v0.z, (bf16)v0.w,
                 (bf16)v1.x, (bf16)v1.y, (bf16)v1.z, (bf16)v1.w };
    *(bf16x8*)((bf16*)(src + (size_t)row * 512) + l * 8) = h;
}

// ---------- qkv GEMM: M=32768 N=1536 K=512, 128x128 tiles ----------
extern "C" __global__ __launch_bounds__(256, 3)
void qkv_kernel(const char* __restrict__ xb, const bf16* __restrict__ Wqkv,
                const float* __restrict__ bqkv, char* __restrict__ qOb,
                char* __restrict__ kvb) {
    extern __shared__ char smem[];
    const int tid = threadIdx.x;
    const int wid = tid >> 6, lane = tid & 63, l16 = lane & 15, quad = lane >> 4;
    const int wm = wid >> 1, wn = wid & 1;
    const int rb = blockIdx.x, cb = blockIdx.y;
    f32x4 acc[4][4];
#pragma unroll
    for (int i = 0; i < 4; ++i)
#pragma unroll
        for (int nt = 0; nt < 4; ++nt) acc[i][nt] = (f32x4){0.f, 0.f, 0.f, 0.f};

#pragma unroll 1
    for (int kstep = 0; kstep < 8; ++kstep) {
        // stage B tile 128x64 bf16 -> LDS (swizzled, rs=128B)
        {
            int lr = tid >> 1, half = tid & 1;
            const char* g = (const char*)(Wqkv + (size_t)(cb * 128 + lr) * 512 + kstep * 64 + half * 32);
#pragma unroll
            for (int c = 0; c < 4; ++c) {
                bf16x8 v = *(const bf16x8*)(g + c * 16);
                *(bf16x8*)(smem + swz(0, lr, 128, half * 64 + c * 16)) = v;
            }
        }
        __syncthreads();
#pragma unroll
        for (int k16 = 0; k16 < 2; ++k16) {
            bf16x8 a[4];
#pragma unroll
            for (int i = 0; i < 4; ++i) {
                int row = rb * 128 + wm * 64 + i * 16 + l16;
                a[i] = *(const bf16x8*)(xb + (size_t)row * 2048 + (kstep * 64 + k16 * 32 + quad * 8) * 2);
            }
#pragma unroll
            for (int nt = 0; nt < 4; ++nt) {
                bf16x8 b = *(bf16x8*)(smem + swz(0, wn * 64 + nt * 16 + l16, 128, k16 * 64 + quad * 16));
#pragma unroll
                for (int i = 0; i < 4; ++i) acc[i][nt] = MFMA16(a[i], b, acc[i][nt]);
            }
        }
        __syncthreads();
    }
    const int region = cb >> 2;  // 0=q, 1=k, 2=v (uniform per block)
#pragma unroll
    for (int nt = 0; nt < 4; ++nt) {
        int n_g = cb * 128 + wn * 64 + nt * 16 + l16;
        float bias = bqkv[n_g];
        int nl = n_g - region * 512;
#pragma unroll
        for (int i = 0; i < 4; ++i)
#pragma unroll
            for (int r = 0; r < 4; ++r) {
                int row = rb * 128 + wm * 64 + i * 16 + quad * 4 + r;
                bf16 v = (bf16)(acc[i][nt][r] + bias);
                if (region == 0)      *(bf16*)(qOb + (size_t)row * 1024 + nl * 2) = v;
                else if (region == 1) *(bf16*)(kvb + (size_t)row * 2048 + nl * 2) = v;
                else                  *(bf16*)(kvb + (size_t)row * 2048 + 1024 + nl * 2) = v;
            }
    }
}

// ---------- attention: one block per (window, head) ----------
#define AVT 0u       // vT 64x128 bf16 rs=256B (16KB)
#define ASCR 16384u  // 8 waves x 2KB transpose scratch
extern "C" __global__ __launch_bounds__(512, 4)
void attn_kernel(char* __restrict__ qOb, const char* __restrict__ kvb) {
    extern __shared__ char smem[];
    const int tid = threadIdx.x;
    const int wid = tid >> 6, lane = tid & 63, l16 = lane & 15, quad = lane >> 4;
    const int win = blockIdx.x >> 3, head = blockIdx.x & 7;
    const size_t wrow0 = (size_t)win * 128;
    f32x4 zero4 = { 0.f, 0.f, 0.f, 0.f };

    // stage vT[dim][key] from v rows
    {
        int key = tid >> 2, d0 = (tid & 3) * 16;
        const char* vs = kvb + (wrow0 + key) * 2048 + 1024 + head * 128 + d0 * 2;
#pragma unroll
        for (int j = 0; j < 2; ++j) {
            bf16x8 v = *(const bf16x8*)(vs + j * 16);
#pragma unroll
            for (int e = 0; e < 8; ++e)
                *(bf16*)(smem + swz(AVT, d0 + j * 8 + e, 256, key * 2)) = v[e];
        }
    }
    __syncthreads();  // only barrier in this kernel

    // q fragments (A layout, direct from global)
    bf16x8 qf[2];
#pragma unroll
    for (int ks = 0; ks < 2; ++ks)
        qf[ks] = *(const bf16x8*)(qOb + (wrow0 + wid * 16 + l16) * 1024 + head * 128 + ks * 64 + quad * 16);

    // scores (k B-frags direct from global)
    f32x4 sa[8];
#pragma unroll
    for (int nt = 0; nt < 8; ++nt) sa[nt] = zero4;
#pragma unroll
    for (int nt = 0; nt < 8; ++nt)
#pragma unroll
        for (int ks = 0; ks < 2; ++ks) {
            bf16x8 kb = *(const bf16x8*)(kvb + (wrow0 + nt * 16 + l16) * 2048 + head * 128 + ks * 64 + quad * 16);
            sa[nt] = MFMA16(qf[ks], kb, sa[nt]);
        }
#pragma unroll
    for (int nt = 0; nt < 8; ++nt) sa[nt] *= 0.125f;
#pragma unroll
    for (int r = 0; r < 4; ++r) {
        float m = sa[0][r];
#pragma unroll
        for (int nt = 1; nt < 8; ++nt) m = fmaxf(m, sa[nt][r]);
#pragma unroll
        for (int sft = 1; sft < 16; sft <<= 1) m = fmaxf(m, __shfl_xor(m, sft, 64));
        float s = 0.f;
#pragma unroll
        for (int nt = 0; nt < 8; ++nt) {
            float e = __expf(sa[nt][r] - m);
            sa[nt][r] = e;
            s += e;
        }
#pragma unroll
        for (int sft = 1; sft < 16; sft <<= 1) s += __shfl_xor(s, sft, 64);
        float inv = 1.0f / s;
#pragma unroll
        for (int nt = 0; nt < 8; ++nt) sa[nt][r] *= inv;
    }

    // P C->A transpose through wave-private scratch
    const uint32_t sb = ASCR + (uint32_t)wid * 2048;
    bf16x8 pf[4];
#pragma unroll
    for (int hf = 0; hf < 2; ++hf) {
#pragma unroll
        for (int nt = 0; nt < 4; ++nt)
#pragma unroll
            for (int r = 0; r < 4; ++r)
                *(bf16*)(smem + swz(sb, quad * 4 + r, 128, (nt * 16 + l16) * 2)) = (bf16)sa[hf * 4 + nt][r];
        asm volatile("s_waitcnt lgkmcnt(0)" ::: "memory");
#pragma unroll
        for (int ks = 0; ks < 2; ++ks)
            pf[hf * 2 + ks] = *(bf16x8*)(smem + swz(sb, l16, 128, ks * 64 + quad * 16));
        asm volatile("s_waitcnt lgkmcnt(0)" ::: "memory");
    }

    // O = P @ V -> overwrite q slot (same rows/cols as this block's q)
#pragma unroll
    for (int nt = 0; nt < 4; ++nt) {
        f32x4 ov = zero4;
#pragma unroll
        for (int ks = 0; ks < 4; ++ks) {
            bf16x8 vb = *(bf16x8*)(smem + swz(AVT, nt * 16 + l16, 256, ks * 64 + quad * 16));
            ov = MFMA16(pf[ks], vb, ov);
        }
#pragma unroll
        for (int r = 0; r < 4; ++r)
            *(bf16*)(qOb + (wrow0 + wid * 16 + quad * 4 + r) * 1024 + head * 128 + (nt * 16 + l16) * 2) = (bf16)ov[r];
    }
}

// ---------- out-proj + residual + LN1: M=32768 N=512 K=512 ----------
extern "C" __global__ __launch_bounds__(256, 2)
void outproj_kernel(char* __restrict__ srcb, const char* __restrict__ qOb,
                    const bf16* __restrict__ Wout, const float* __restrict__ bout,
                    const float* __restrict__ g1, const float* __restrict__ be1) {
    extern __shared__ char smem[];
    const int tid = threadIdx.x;
    const int wid = tid >> 6, lane = tid & 63, l16 = lane & 15, quad = lane >> 4;
    const int mb = blockIdx.x;
    f32x4 acc[32];
#pragma unroll
    for (int nt = 0; nt < 32; ++nt) acc[nt] = (f32x4){0.f, 0.f, 0.f, 0.f};

#pragma unroll 1
    for (int kstep = 0; kstep < 8; ++kstep) {
        {
            int n0 = tid * 2;
#pragma unroll
            for (int rr = 0; rr < 2; ++rr) {
                int n = n0 + rr;
                const char* g = (const char*)(Wout + (size_t)n * 512 + kstep * 64);
#pragma unroll
                for (int c = 0; c < 8; ++c) {
                    bf16x8 v = *(const bf16x8*)(g + c * 16);
                    *(bf16x8*)(smem + swz(0, n, 128, c * 16)) = v;
                }
            }
        }
        __syncthreads();
#pragma unroll
        for (int k16 = 0; k16 < 2; ++k16) {
            bf16x8 a = *(const bf16x8*)(qOb + (size_t)(mb * 64 + wid * 16 + l16) * 1024 +
                                        (kstep * 64 + k16 * 32 + quad * 8) * 2);
#pragma unroll
            for (int nt = 0; nt < 32; ++nt) {
                bf16x8 b = *(bf16x8*)(smem + swz(0, nt * 16 + l16, 128, k16 * 64 + quad * 16));
                acc[nt] = MFMA16(a, b, acc[nt]);
            }
        }
        __syncthreads();
    }
    // bias + residual (bf16 x) + LN1 (wave owns full row) -> x1
#pragma unroll
    for (int nt = 0; nt < 32; ++nt) {
        int col = nt * 16 + l16;
        float bb = bout[col];
#pragma unroll
        for (int r = 0; r < 4; ++r) {
            int row = mb * 64 + wid * 16 + quad * 4 + r;
            float xv = (float)*(const bf16*)(srcb + (size_t)row * 2048 + col * 2);
            acc[nt][r] += bb + xv;
        }
    }
#pragma unroll
    for (int r = 0; r < 4; ++r) {
        float s = 0.f, s2 = 0.f;
#pragma unroll
        for (int nt = 0; nt < 32; ++nt) {
            float v = acc[nt][r];
            s += v;
            s2 += v * v;
        }
#pragma unroll
        for (int sft = 1; sft < 16; sft <<= 1) {
            s += __shfl_xor(s, sft, 64);
            s2 += __shfl_xor(s2, sft, 64);
        }
        float mu = s * (1.0f / 512.0f);
        float var = s2 * (1.0f / 512.0f) - mu * mu;
        float rstd = rsqrtf(var + 1e-5f);
        int row = mb * 64 + wid * 16 + quad * 4 + r;
#pragma unroll
        for (int nt = 0; nt < 32; ++nt) {
            int col = nt * 16 + l16;
            float v = (acc[nt][r] - mu) * rstd * g1[col] + be1[col];
            *(bf16*)(srcb + (size_t)row * 2048 + 1024 + col * 2) = (bf16)v;
        }
    }
}

// ---------- FF1: M=32768 N=2048 K=512, relu, h -> 3-region scratch ----------
extern "C" __global__ __launch_bounds__(256, 3)
void ff1_kernel(char* __restrict__ srcb, const bf16* __restrict__ W1,
                const float* __restrict__ b1, char* __restrict__ doutb,
                char* __restrict__ wsOb) {
    extern __shared__ char smem[];
    const int tid = threadIdx.x;
    const int wid = tid >> 6, lane = tid & 63, l16 = lane & 15, quad = lane >> 4;
    const int mb = blockIdx.x, cb = blockIdx.y;
    f32x4 acc[16];
#pragma unroll
    for (int nt = 0; nt < 16; ++nt) acc[nt] = (f32x4){0.f, 0.f, 0.f, 0.f};

#pragma unroll 1
    for (int kstep = 0; kstep < 8; ++kstep) {
        {
            const char* g = (const char*)(W1 + (size_t)(cb * 256 + tid) * 512 + kstep * 64);
#pragma unroll
            for (int c = 0; c < 8; ++c) {
                bf16x8 v = *(const bf16x8*)(g + c * 16);
                *(bf16x8*)(smem + swz(0, tid, 128, c * 16)) = v;
            }
        }
        __syncthreads();
#pragma unroll
        for (int k16 = 0; k16 < 2; ++k16) {
            bf16x8 a = *(const bf16x8*)(srcb + (size_t)(mb * 64 + wid * 16 + l16) * 2048 + 1024 +
                                        (kstep * 64 + k16 * 32 + quad * 8) * 2);
#pragma unroll
            for (int nt = 0; nt < 16; ++nt) {
                bf16x8 b = *(bf16x8*)(smem + swz(0, nt * 16 + l16, 128, k16 * 64 + quad * 16));
                acc[nt] = MFMA16(a, b, acc[nt]);
            }
        }
        __syncthreads();
    }
#pragma unroll
    for (int nt = 0; nt < 16; ++nt) {
        int col = cb * 256 + nt * 16 + l16;
        float bb = b1[col];
#pragma unroll
        for (int r = 0; r < 4; ++r) {
            int row = mb * 64 + wid * 16 + quad * 4 + r;
            bf16 v = (bf16)fmaxf(acc[nt][r] + bb, 0.0f);
            if (cb < 4)      *(bf16*)(doutb + (size_t)row * 2048 + col * 2) = v;
            else if (cb < 6) *(bf16*)(srcb + (size_t)row * 2048 + (col - 1024) * 2) = v;
            else             *(bf16*)(wsOb + (size_t)row * 1024 + (col - 1536) * 2) = v;
        }
    }
}

// ---------- FF2 + residual + LN2: M=32768 N=512 K=2048 -> f32 out ----------
extern "C" __global__ __launch_bounds__(256, 2)
void ff2_kernel(char* __restrict__ doutb, const char* __restrict__ srcb,
                const char* __restrict__ wsOb, const bf16* __restrict__ W2,
                const float* __restrict__ b2, const float* __restrict__ g2,
                const float* __restrict__ be2) {
    extern __shared__ char smem[];
    const int tid = threadIdx.x;
    const int wid = tid >> 6, lane = tid & 63, l16 = lane & 15, quad = lane >> 4;
    const int mb = blockIdx.x;
    f32x4 acc[32];
#pragma unroll
    for (int nt = 0; nt < 32; ++nt) acc[nt] = (f32x4){0.f, 0.f, 0.f, 0.f};

#pragma unroll 1
    for (int kstep = 0; kstep < 32; ++kstep) {
        {
            int n0 = tid * 2;
#pragma unroll
            for (int rr = 0; rr < 2; ++rr) {
                int n = n0 + rr;
                const char* g = (const char*)(W2 + (size_t)n * 2048 + kstep * 64);
#pragma unroll
                for (int c = 0; c < 8; ++c) {
                    bf16x8 v = *(const bf16x8*)(g + c * 16);
                    *(bf16x8*)(smem + swz(0, n, 128, c * 16)) = v;
                }
            }
        }
        __syncthreads();
        const char* hb;
        int hstride, koff;
        if (kstep < 16)      { hb = doutb; hstride = 2048; koff = kstep * 64; }
        else if (kstep < 24) { hb = srcb;  hstride = 2048; koff = kstep * 64 - 1024; }
        else                 { hb = wsOb;  hstride = 1024; koff = kstep * 64 - 1536; }
#pragma unroll
        for (int k16 = 0; k16 < 2; ++k16) {
            bf16x8 a = *(const bf16x8*)(hb + (size_t)(mb * 64 + wid * 16 + l16) * hstride +
                                        (koff + k16 * 32 + quad * 8) * 2);
#pragma unroll
            for (int nt = 0; nt < 32; ++nt) {
                bf16x8 b = *(bf16x8*)(smem + swz(0, nt * 16 + l16, 128, k16 * 64 + quad * 16));
                acc[nt] = MFMA16(a, b, acc[nt]);
            }
        }
        __syncthreads();
    }
    // bias + residual(x1) + LN2 -> f32 out (overwrites h[0:1024] after consumption)
#pragma unroll
    for (int nt = 0; nt < 32; ++nt) {
        int col = nt * 16 + l16;
        float bb = b2[col];
#pragma unroll
        for (int r = 0; r < 4; ++r) {
            int row = mb * 64 + wid * 16 + quad * 4 + r;
            float x1v = (float)*(const bf16*)(srcb + (size_t)row * 2048 + 1024 + col * 2);
            acc[nt][r] += bb + x1v;
        }
    }
#pragma unroll
    for (int r = 0; r < 4; ++r) {
        float s = 0.f, s2 = 0.f;
#pragma unroll
        for (int nt = 0; nt < 32; ++nt) {
            float v = acc[nt][r];
            s += v;
            s2 += v * v;
        }
#pragma unroll
        for (int sft = 1; sft < 16; sft <<= 1) {
            s += __shfl_xor(s, sft, 64);
            s2 += __shfl_xor(s2, sft, 64);
        }
        float mu = s * (1.0f / 512.0f);
        float var = s2 * (1.0f / 512.0f) - mu * mu;
        float rstd = rsqrtf(var + 1e-5f);
        int row = mb * 64 + wid * 16 + quad * 4 + r;
#pragma unroll
        for (int nt = 0; nt < 32; ++nt) {
            int col = nt * 16 + l16;
            *(float*)(doutb + (size_t)row * 2048 + col * 4) =
                (acc[nt][r] - mu) * rstd * g2[col] + be2[col];
        }
    }
}

extern "C" void kernel_launch(void* const* d_in, const int* in_sizes, int n_in,
                              void* d_out, int out_size, void* d_ws, size_t ws_size,
                              hipStream_t stream) {
    (void)in_sizes; (void)n_in; (void)out_size; (void)ws_size;
    float* src = (float*)d_in[0];
    const float* ipw = (const float*)d_in[1];
    const float* ipb = (const float*)d_in[2];
    const float* ow  = (const float*)d_in[3];
    const float* ob  = (const float*)d_in[4];
    const float* g1  = (const float*)d_in[5];
    const float* be1 = (const float*)d_in[6];
    const float* w1  = (const float*)d_in[7];
    const float* b1  = (const float*)d_in[8];
    const float* w2  = (const float*)d_in[9];
    const float* b2  = (const float*)d_in[10];
    const float* g2  = (const float*)d_in[11];
    const float* be2 = (const float*)d_in[12];
    bf16* ws = (bf16*)d_ws;
    char* srcb = (char*)src;
    char* doutb = (char*)d_out;
    char* qOb = (char*)d_ws + 6291456;  // 33.5 MB q/O/h-tail region

    wcvt_kernel<<<3072, 256, 0, stream>>>(ipw, ow, w1, w2, ws);
    xcvt_kernel<<<8192, 256, 0, stream>>>(src);

    hipFuncSetAttribute((const void*)qkv_kernel, hipFuncAttributeMaxDynamicSharedMemorySize, 16384);
    hipFuncSetAttribute((const void*)attn_kernel, hipFuncAttributeMaxDynamicSharedMemorySize, 32768);
    hipFuncSetAttribute((const void*)outproj_kernel, hipFuncAttributeMaxDynamicSharedMemorySize, 65536);
    hipFuncSetAttribute((const void*)ff1_kernel, hipFuncAttributeMaxDynamicSharedMemorySize, 32768);
    hipFuncSetAttribute((const void*)ff2_kernel, hipFuncAttributeMaxDynamicSharedMemorySize, 65536);

    qkv_kernel<<<dim3(256, 12), 256, 16384, stream>>>(srcb, ws, ipb, qOb, doutb);
    attn_kernel<<<2048, 512, 32768, stream>>>(qOb, doutb);
    outproj_kernel<<<512, 256, 65536, stream>>>(srcb, qOb, ws + 786432, ob, g1, be1);
    ff1_kernel<<<dim3(512, 8), 256, 32768, stream>>>(srcb, ws + 1048576, b1, doutb, qOb);
    ff2_kernel<<<512, 256, 65536, stream>>>(doutb, srcb, qOb, ws + 2097152, b2, g2, be2);
}

// Round 8
// 726.817 us; speedup vs baseline: 1.1331x; 1.1331x over previous
//
#include <hip/hip_runtime.h>
#include <hip/hip_bf16.h>
#include <math.h>

typedef __bf16 bf16;
typedef bf16 bf16x8 __attribute__((ext_vector_type(8)));
typedef bf16 bf16x4 __attribute__((ext_vector_type(4)));
typedef float f32x4 __attribute__((ext_vector_type(4)));

#define MFMA16(a, b, c) __builtin_amdgcn_mfma_f32_16x16x32_bf16(a, b, c, 0, 0, 0)

// XOR-swizzle on 16B chunks within a row: breaks power-of-2 row-stride bank aliasing.
__device__ __forceinline__ uint32_t swz(uint32_t base, uint32_t row, uint32_t rs, uint32_t cb) {
    return base + row * rs + (((cb >> 4) ^ (row & 7u)) << 4) + (cb & 15u);
}

// Scratch map (row r = one of 32768 tokens):
//  src  slice r*2048B: [0,1024)=x_bf16 (xcvt; dead after outproj) -> h[1024:1536]
//                      [1024,2048)=x1 bf16 (outproj; read ff1, ff2-residual)
//  dout slice r*2048B: [0,1024)=k, [1024,2048)=v (qkv; dead after attn)
//                      -> h[0:1024] (ff1) -> final f32 out row (ff2, after h consumed)
//  ws: [0,6.3MB)=bf16 weights; [6.3,39.8MB) r*1024B: q (qkv) -> O (attn, same
//      block/cols) -> h[1536:2048] (ff1)
// All bf16 intermediate stores go through a per-wave LDS transpose (B-staging
// region reused after the K-loop) so global stores are 16B/lane, row-contiguous.

// ---------- weights f32 -> bf16 ----------
__global__ void wcvt_kernel(const float* __restrict__ w0, const float* __restrict__ w1,
                            const float* __restrict__ w2, const float* __restrict__ w3,
                            bf16* __restrict__ o) {
    int i = blockIdx.x * blockDim.x + threadIdx.x;
    int e = i * 4;
    const float* s;
    int off;
    if (e < 786432)       { s = w0; off = e; }
    else if (e < 1048576) { s = w1; off = e - 786432; }
    else if (e < 2097152) { s = w2; off = e - 1048576; }
    else                  { s = w3; off = e - 2097152; }
    float4 v = *(const float4*)(s + off);
    bf16x4 h = { (bf16)v.x, (bf16)v.y, (bf16)v.z, (bf16)v.w };
    *(bf16x4*)(o + e) = h;
}

// ---------- src f32 -> bf16 in place (row-aligned slot; wave per row) ----------
__global__ void xcvt_kernel(float* __restrict__ src) {
    int row = blockIdx.x * 4 + (threadIdx.x >> 6);
    int l = threadIdx.x & 63;
    float* rp = src + (size_t)row * 512 + l * 8;
    float4 v0 = *(const float4*)rp;
    float4 v1 = *(const float4*)(rp + 4);
    asm volatile("s_waitcnt vmcnt(0)" ::: "memory");  // all wave reads before any write
    bf16x8 h = { (bf16)v0.x, (bf16)v0.y, (bf16)v0.z, (bf16)v0.w,
                 (bf16)v1.x, (bf16)v1.y, (bf16)v1.z, (bf16)v1.w };
    *(bf16x8*)((bf16*)(src + (size_t)row * 512) + l * 8) = h;
}

// ---------- qkv GEMM: M=32768 N=1536 K=512, 128x128 tiles ----------
extern "C" __global__ __launch_bounds__(256, 3)
void qkv_kernel(const char* __restrict__ xb, const bf16* __restrict__ Wqkv,
                const float* __restrict__ bqkv, char* __restrict__ qOb,
                char* __restrict__ kvb) {
    extern __shared__ char smem[];
    const int tid = threadIdx.x;
    const int wid = tid >> 6, lane = tid & 63, l16 = lane & 15, quad = lane >> 4;
    const int wm = wid >> 1, wn = wid & 1;
    const int rb = blockIdx.x, cb = blockIdx.y;
    f32x4 acc[4][4];
#pragma unroll
    for (int i = 0; i < 4; ++i)
#pragma unroll
        for (int nt = 0; nt < 4; ++nt) acc[i][nt] = (f32x4){0.f, 0.f, 0.f, 0.f};

#pragma unroll 1
    for (int kstep = 0; kstep < 8; ++kstep) {
        // stage B tile 128x64 bf16 -> LDS (swizzled, rs=128B)
        {
            int lr = tid >> 1, half = tid & 1;
            const char* g = (const char*)(Wqkv + (size_t)(cb * 128 + lr) * 512 + kstep * 64 + half * 32);
#pragma unroll
            for (int c = 0; c < 4; ++c) {
                bf16x8 v = *(const bf16x8*)(g + c * 16);
                *(bf16x8*)(smem + swz(0, lr, 128, half * 64 + c * 16)) = v;
            }
        }
        __syncthreads();
#pragma unroll
        for (int k16 = 0; k16 < 2; ++k16) {
            bf16x8 a[4];
#pragma unroll
            for (int i = 0; i < 4; ++i) {
                int row = rb * 128 + wm * 64 + i * 16 + l16;
                a[i] = *(const bf16x8*)(xb + (size_t)row * 2048 + (kstep * 64 + k16 * 32 + quad * 8) * 2);
            }
#pragma unroll
            for (int nt = 0; nt < 4; ++nt) {
                bf16x8 b = *(bf16x8*)(smem + swz(0, wn * 64 + nt * 16 + l16, 128, k16 * 64 + quad * 16));
#pragma unroll
                for (int i = 0; i < 4; ++i) acc[i][nt] = MFMA16(a[i], b, acc[i][nt]);
            }
        }
        __syncthreads();  // after last iter: B region dead -> transpose scratch
    }
    // ---- bias + C->rowmajor transpose through wave-private LDS (8KB/wave) ----
    const uint32_t wb = (uint32_t)wid * 8192;  // 64 rows x 128B
#pragma unroll
    for (int nt = 0; nt < 4; ++nt) {
        float bias = bqkv[cb * 128 + wn * 64 + nt * 16 + l16];
#pragma unroll
        for (int i = 0; i < 4; ++i)
#pragma unroll
            for (int r = 0; r < 4; ++r)
                *(bf16*)(smem + swz(wb, i * 16 + quad * 4 + r, 128, (nt * 16 + l16) * 2)) =
                    (bf16)(acc[i][nt][r] + bias);
    }
    asm volatile("s_waitcnt lgkmcnt(0)" ::: "memory");
    const int region = cb >> 2;  // 0=q, 1=k, 2=v (uniform per block)
#pragma unroll
    for (int c = 0; c < 8; ++c) {
        int lr = c * 8 + (lane >> 3), ch = lane & 7;
        bf16x8 v = *(bf16x8*)(smem + swz(wb, lr, 128, ch * 16));
        int row_g = rb * 128 + wm * 64 + lr;
        int colb = (cb * 128 + wn * 64) * 2 + ch * 16;  // byte col in 1536*2 space
        if (region == 0)      *(bf16x8*)(qOb + (size_t)row_g * 1024 + colb) = v;
        else if (region == 1) *(bf16x8*)(kvb + (size_t)row_g * 2048 + (colb - 1024)) = v;
        else                  *(bf16x8*)(kvb + (size_t)row_g * 2048 + 1024 + (colb - 2048)) = v;
    }
}

// ---------- attention: one block per (window, head) ----------
#define AVT 0u       // vT 64x128 bf16 rs=256B (16KB)
#define ASCR 16384u  // 8 waves x 2KB transpose scratch
extern "C" __global__ __launch_bounds__(512, 4)
void attn_kernel(char* __restrict__ qOb, const char* __restrict__ kvb) {
    extern __shared__ char smem[];
    const int tid = threadIdx.x;
    const int wid = tid >> 6, lane = tid & 63, l16 = lane & 15, quad = lane >> 4;
    const int win = blockIdx.x >> 3, head = blockIdx.x & 7;
    const size_t wrow0 = (size_t)win * 128;
    f32x4 zero4 = { 0.f, 0.f, 0.f, 0.f };

    // stage vT[dim][key] from v rows
    {
        int key = tid >> 2, d0 = (tid & 3) * 16;
        const char* vs = kvb + (wrow0 + key) * 2048 + 1024 + head * 128 + d0 * 2;
#pragma unroll
        for (int j = 0; j < 2; ++j) {
            bf16x8 v = *(const bf16x8*)(vs + j * 16);
#pragma unroll
            for (int e = 0; e < 8; ++e)
                *(bf16*)(smem + swz(AVT, d0 + j * 8 + e, 256, key * 2)) = v[e];
        }
    }
    __syncthreads();  // only barrier in this kernel

    // q fragments (A layout, direct from global)
    bf16x8 qf[2];
#pragma unroll
    for (int ks = 0; ks < 2; ++ks)
        qf[ks] = *(const bf16x8*)(qOb + (wrow0 + wid * 16 + l16) * 1024 + head * 128 + ks * 64 + quad * 16);

    // scores (k B-frags direct from global)
    f32x4 sa[8];
#pragma unroll
    for (int nt = 0; nt < 8; ++nt) sa[nt] = zero4;
#pragma unroll
    for (int nt = 0; nt < 8; ++nt)
#pragma unroll
        for (int ks = 0; ks < 2; ++ks) {
            bf16x8 kb = *(const bf16x8*)(kvb + (wrow0 + nt * 16 + l16) * 2048 + head * 128 + ks * 64 + quad * 16);
            sa[nt] = MFMA16(qf[ks], kb, sa[nt]);
        }
#pragma unroll
    for (int nt = 0; nt < 8; ++nt) sa[nt] *= 0.125f;
#pragma unroll
    for (int r = 0; r < 4; ++r) {
        float m = sa[0][r];
#pragma unroll
        for (int nt = 1; nt < 8; ++nt) m = fmaxf(m, sa[nt][r]);
#pragma unroll
        for (int sft = 1; sft < 16; sft <<= 1) m = fmaxf(m, __shfl_xor(m, sft, 64));
        float s = 0.f;
#pragma unroll
        for (int nt = 0; nt < 8; ++nt) {
            float e = __expf(sa[nt][r] - m);
            sa[nt][r] = e;
            s += e;
        }
#pragma unroll
        for (int sft = 1; sft < 16; sft <<= 1) s += __shfl_xor(s, sft, 64);
        float inv = 1.0f / s;
#pragma unroll
        for (int nt = 0; nt < 8; ++nt) sa[nt][r] *= inv;
    }

    // P C->A transpose through wave-private scratch
    const uint32_t sb = ASCR + (uint32_t)wid * 2048;
    bf16x8 pf[4];
#pragma unroll
    for (int hf = 0; hf < 2; ++hf) {
#pragma unroll
        for (int nt = 0; nt < 4; ++nt)
#pragma unroll
            for (int r = 0; r < 4; ++r)
                *(bf16*)(smem + swz(sb, quad * 4 + r, 128, (nt * 16 + l16) * 2)) = (bf16)sa[hf * 4 + nt][r];
        asm volatile("s_waitcnt lgkmcnt(0)" ::: "memory");
#pragma unroll
        for (int ks = 0; ks < 2; ++ks)
            pf[hf * 2 + ks] = *(bf16x8*)(smem + swz(sb, l16, 128, ks * 64 + quad * 16));
        asm volatile("s_waitcnt lgkmcnt(0)" ::: "memory");
    }

    // O = P @ V
    f32x4 ov[4];
#pragma unroll
    for (int nt = 0; nt < 4; ++nt) {
        ov[nt] = zero4;
#pragma unroll
        for (int ks = 0; ks < 4; ++ks) {
            bf16x8 vb = *(bf16x8*)(smem + swz(AVT, nt * 16 + l16, 256, ks * 64 + quad * 16));
            ov[nt] = MFMA16(pf[ks], vb, ov[nt]);
        }
    }
    // O store via transpose: two 32-col halves through 2KB wave scratch (rs=128)
#pragma unroll
    for (int hf = 0; hf < 2; ++hf) {
#pragma unroll
        for (int nt = 0; nt < 2; ++nt)
#pragma unroll
            for (int r = 0; r < 4; ++r)
                *(bf16*)(smem + swz(sb, quad * 4 + r, 128, (nt * 16 + l16) * 2)) = (bf16)ov[hf * 2 + nt][r];
        asm volatile("s_waitcnt lgkmcnt(0)" ::: "memory");
        {
            int row = lane >> 2, ch = lane & 3;
            bf16x8 v = *(bf16x8*)(smem + swz(sb, row, 128, ch * 16));
            *(bf16x8*)(qOb + (wrow0 + wid * 16 + row) * 1024 + head * 128 + hf * 64 + ch * 16) = v;
        }
        asm volatile("s_waitcnt lgkmcnt(0)" ::: "memory");
    }
}

// ---------- out-proj + residual + LN1: M=32768 N=512 K=512 ----------
extern "C" __global__ __launch_bounds__(256, 2)
void outproj_kernel(char* __restrict__ srcb, const char* __restrict__ qOb,
                    const bf16* __restrict__ Wout, const float* __restrict__ bout,
                    const float* __restrict__ g1, const float* __restrict__ be1) {
    extern __shared__ char smem[];
    const int tid = threadIdx.x;
    const int wid = tid >> 6, lane = tid & 63, l16 = lane & 15, quad = lane >> 4;
    const int mb = blockIdx.x;
    f32x4 acc[32];
#pragma unroll
    for (int nt = 0; nt < 32; ++nt) acc[nt] = (f32x4){0.f, 0.f, 0.f, 0.f};

#pragma unroll 1
    for (int kstep = 0; kstep < 8; ++kstep) {
        {
            int n0 = tid * 2;
#pragma unroll
            for (int rr = 0; rr < 2; ++rr) {
                int n = n0 + rr;
                const char* g = (const char*)(Wout + (size_t)n * 512 + kstep * 64);
#pragma unroll
                for (int c = 0; c < 8; ++c) {
                    bf16x8 v = *(const bf16x8*)(g + c * 16);
                    *(bf16x8*)(smem + swz(0, n, 128, c * 16)) = v;
                }
            }
        }
        __syncthreads();
#pragma unroll
        for (int k16 = 0; k16 < 2; ++k16) {
            bf16x8 a = *(const bf16x8*)(qOb + (size_t)(mb * 64 + wid * 16 + l16) * 1024 +
                                        (kstep * 64 + k16 * 32 + quad * 8) * 2);
#pragma unroll
            for (int nt = 0; nt < 32; ++nt) {
                bf16x8 b = *(bf16x8*)(smem + swz(0, nt * 16 + l16, 128, k16 * 64 + quad * 16));
                acc[nt] = MFMA16(a, b, acc[nt]);
            }
        }
        __syncthreads();  // after last iter: B region dead -> transpose scratch
    }
    // bias + residual (bf16 x) + LN1 (wave owns full row)
#pragma unroll
    for (int nt = 0; nt < 32; ++nt) {
        int col = nt * 16 + l16;
        float bb = bout[col];
#pragma unroll
        for (int r = 0; r < 4; ++r) {
            int row = mb * 64 + wid * 16 + quad * 4 + r;
            float xv = (float)*(const bf16*)(srcb + (size_t)row * 2048 + col * 2);
            acc[nt][r] += bb + xv;
        }
    }
    const uint32_t wb = (uint32_t)wid * 16384;  // 16 rows x 1024B
#pragma unroll
    for (int r = 0; r < 4; ++r) {
        float s = 0.f, s2 = 0.f;
#pragma unroll
        for (int nt = 0; nt < 32; ++nt) {
            float v = acc[nt][r];
            s += v;
            s2 += v * v;
        }
#pragma unroll
        for (int sft = 1; sft < 16; sft <<= 1) {
            s += __shfl_xor(s, sft, 64);
            s2 += __shfl_xor(s2, sft, 64);
        }
        float mu = s * (1.0f / 512.0f);
        float var = s2 * (1.0f / 512.0f) - mu * mu;
        float rstd = rsqrtf(var + 1e-5f);
#pragma unroll
        for (int nt = 0; nt < 32; ++nt) {
            int col = nt * 16 + l16;
            float v = (acc[nt][r] - mu) * rstd * g1[col] + be1[col];
            *(bf16*)(smem + swz(wb, quad * 4 + r, 1024, col * 2)) = (bf16)v;
        }
    }
    asm volatile("s_waitcnt lgkmcnt(0)" ::: "memory");
#pragma unroll
    for (int t = 0; t < 16; ++t) {
        int row = (t >> 2) * 4 + (lane >> 4);
        int ch = (t & 3) * 16 + l16;
        bf16x8 v = *(bf16x8*)(smem + swz(wb, row, 1024, ch * 16));
        *(bf16x8*)(srcb + (size_t)(mb * 64 + wid * 16 + row) * 2048 + 1024 + ch * 16) = v;
    }
}

// ---------- FF1: M=32768 N=2048 K=512, relu, h -> 3-region scratch ----------
extern "C" __global__ __launch_bounds__(256, 3)
void ff1_kernel(char* __restrict__ srcb, const bf16* __restrict__ W1,
                const float* __restrict__ b1, char* __restrict__ doutb,
                char* __restrict__ wsOb) {
    extern __shared__ char smem[];
    const int tid = threadIdx.x;
    const int wid = tid >> 6, lane = tid & 63, l16 = lane & 15, quad = lane >> 4;
    const int mb = blockIdx.x, cb = blockIdx.y;
    f32x4 acc[16];
#pragma unroll
    for (int nt = 0; nt < 16; ++nt) acc[nt] = (f32x4){0.f, 0.f, 0.f, 0.f};

#pragma unroll 1
    for (int kstep = 0; kstep < 8; ++kstep) {
        {
            const char* g = (const char*)(W1 + (size_t)(cb * 256 + tid) * 512 + kstep * 64);
#pragma unroll
            for (int c = 0; c < 8; ++c) {
                bf16x8 v = *(const bf16x8*)(g + c * 16);
                *(bf16x8*)(smem + swz(0, tid, 128, c * 16)) = v;
            }
        }
        __syncthreads();
#pragma unroll
        for (int k16 = 0; k16 < 2; ++k16) {
            bf16x8 a = *(const bf16x8*)(srcb + (size_t)(mb * 64 + wid * 16 + l16) * 2048 + 1024 +
                                        (kstep * 64 + k16 * 32 + quad * 8) * 2);
#pragma unroll
            for (int nt = 0; nt < 16; ++nt) {
                bf16x8 b = *(bf16x8*)(smem + swz(0, nt * 16 + l16, 128, k16 * 64 + quad * 16));
                acc[nt] = MFMA16(a, b, acc[nt]);
            }
        }
        __syncthreads();  // after last iter: B region dead -> transpose scratch
    }
    // bias + relu -> wave-private LDS tile (16 rows x 512B), then coalesced store
    const uint32_t wb = (uint32_t)wid * 8192;
#pragma unroll
    for (int nt = 0; nt < 16; ++nt) {
        float bb = b1[cb * 256 + nt * 16 + l16];
#pragma unroll
        for (int r = 0; r < 4; ++r)
            *(bf16*)(smem + swz(wb, quad * 4 + r, 512, (nt * 16 + l16) * 2)) =
                (bf16)fmaxf(acc[nt][r] + bb, 0.0f);
    }
    asm volatile("s_waitcnt lgkmcnt(0)" ::: "memory");
#pragma unroll
    for (int t = 0; t < 8; ++t) {
        int row = t * 2 + (lane >> 5);
        int ch = lane & 31;
        bf16x8 v = *(bf16x8*)(smem + swz(wb, row, 512, ch * 16));
        size_t row_g = (size_t)(mb * 64 + wid * 16 + row);
        int colb = ch * 16;  // byte offset within this cb's 512B slice
        if (cb < 4)      *(bf16x8*)(doutb + row_g * 2048 + cb * 512 + colb) = v;
        else if (cb < 6) *(bf16x8*)(srcb + row_g * 2048 + (cb - 4) * 512 + colb) = v;
        else             *(bf16x8*)(wsOb + row_g * 1024 + (cb - 6) * 512 + colb) = v;
    }
}

// ---------- FF2 + residual + LN2: M=32768 N=512 K=2048 -> f32 out ----------
extern "C" __global__ __launch_bounds__(256, 2)
void ff2_kernel(char* __restrict__ doutb, const char* __restrict__ srcb,
                const char* __restrict__ wsOb, const bf16* __restrict__ W2,
                const float* __restrict__ b2, const float* __restrict__ g2,
                const float* __restrict__ be2) {
    extern __shared__ char smem[];
    const int tid = threadIdx.x;
    const int wid = tid >> 6, lane = tid & 63, l16 = lane & 15, quad = lane >> 4;
    const int mb = blockIdx.x;
    f32x4 acc[32];
#pragma unroll
    for (int nt = 0; nt < 32; ++nt) acc[nt] = (f32x4){0.f, 0.f, 0.f, 0.f};

#pragma unroll 1
    for (int kstep = 0; kstep < 32; ++kstep) {
        {
            int n0 = tid * 2;
#pragma unroll
            for (int rr = 0; rr < 2; ++rr) {
                int n = n0 + rr;
                const char* g = (const char*)(W2 + (size_t)n * 2048 + kstep * 64);
#pragma unroll
                for (int c = 0; c < 8; ++c) {
                    bf16x8 v = *(const bf16x8*)(g + c * 16);
                    *(bf16x8*)(smem + swz(0, n, 128, c * 16)) = v;
                }
            }
        }
        __syncthreads();
        const char* hb;
        int hstride, koff;
        if (kstep < 16)      { hb = doutb; hstride = 2048; koff = kstep * 64; }
        else if (kstep < 24) { hb = srcb;  hstride = 2048; koff = kstep * 64 - 1024; }
        else                 { hb = wsOb;  hstride = 1024; koff = kstep * 64 - 1536; }
#pragma unroll
        for (int k16 = 0; k16 < 2; ++k16) {
            bf16x8 a = *(const bf16x8*)(hb + (size_t)(mb * 64 + wid * 16 + l16) * hstride +
                                        (koff + k16 * 32 + quad * 8) * 2);
#pragma unroll
            for (int nt = 0; nt < 32; ++nt) {
                bf16x8 b = *(bf16x8*)(smem + swz(0, nt * 16 + l16, 128, k16 * 64 + quad * 16));
                acc[nt] = MFMA16(a, b, acc[nt]);
            }
        }
        __syncthreads();
    }
    // bias + residual(x1) + LN2 -> f32 out (overwrites h[0:1024] after consumption)
#pragma unroll
    for (int nt = 0; nt < 32; ++nt) {
        int col = nt * 16 + l16;
        float bb = b2[col];
#pragma unroll
        for (int r = 0; r < 4; ++r) {
            int row = mb * 64 + wid * 16 + quad * 4 + r;
            float x1v = (float)*(const bf16*)(srcb + (size_t)row * 2048 + 1024 + col * 2);
            acc[nt][r] += bb + x1v;
        }
    }
#pragma unroll
    for (int r = 0; r < 4; ++r) {
        float s = 0.f, s2 = 0.f;
#pragma unroll
        for (int nt = 0; nt < 32; ++nt) {
            float v = acc[nt][r];
            s += v;
            s2 += v * v;
        }
#pragma unroll
        for (int sft = 1; sft < 16; sft <<= 1) {
            s += __shfl_xor(s, sft, 64);
            s2 += __shfl_xor(s2, sft, 64);
        }
        float mu = s * (1.0f / 512.0f);
        float var = s2 * (1.0f / 512.0f) - mu * mu;
        float rstd = rsqrtf(var + 1e-5f);
        int row = mb * 64 + wid * 16 + quad * 4 + r;
#pragma unroll
        for (int nt = 0; nt < 32; ++nt) {
            int col = nt * 16 + l16;
            *(float*)(doutb + (size_t)row * 2048 + col * 4) =
                (acc[nt][r] - mu) * rstd * g2[col] + be2[col];
        }
    }
}

extern "C" void kernel_launch(void* const* d_in, const int* in_sizes, int n_in,
                              void* d_out, int out_size, void* d_ws, size_t ws_size,
                              hipStream_t stream) {
    (void)in_sizes; (void)n_in; (void)out_size; (void)ws_size;
    float* src = (float*)d_in[0];
    const float* ipw = (const float*)d_in[1];
    const float* ipb = (const float*)d_in[2];
    const float* ow  = (const float*)d_in[3];
    const float* ob  = (const float*)d_in[4];
    const float* g1  = (const float*)d_in[5];
    const float* be1 = (const float*)d_in[6];
    const float* w1  = (const float*)d_in[7];
    const float* b1  = (const float*)d_in[8];
    const float* w2  = (const float*)d_in[9];
    const float* b2  = (const float*)d_in[10];
    const float* g2  = (const float*)d_in[11];
    const float* be2 = (const float*)d_in[12];
    bf16* ws = (bf16*)d_ws;
    char* srcb = (char*)src;
    char* doutb = (char*)d_out;
    char* qOb = (char*)d_ws + 6291456;  // 33.5 MB q/O/h-tail region

    wcvt_kernel<<<3072, 256, 0, stream>>>(ipw, ow, w1, w2, ws);
    xcvt_kernel<<<8192, 256, 0, stream>>>(src);

    hipFuncSetAttribute((const void*)qkv_kernel, hipFuncAttributeMaxDynamicSharedMemorySize, 32768);
    hipFuncSetAttribute((const void*)attn_kernel, hipFuncAttributeMaxDynamicSharedMemorySize, 32768);
    hipFuncSetAttribute((const void*)outproj_kernel, hipFuncAttributeMaxDynamicSharedMemorySize, 65536);
    hipFuncSetAttribute((const void*)ff1_kernel, hipFuncAttributeMaxDynamicSharedMemorySize, 32768);
    hipFuncSetAttribute((const void*)ff2_kernel, hipFuncAttributeMaxDynamicSharedMemorySize, 65536);

    qkv_kernel<<<dim3(256, 12), 256, 32768, stream>>>(srcb, ws, ipb, qOb, doutb);
    attn_kernel<<<2048, 512, 32768, stream>>>(qOb, doutb);
    outproj_kernel<<<512, 256, 65536, stream>>>(srcb, qOb, ws + 786432, ob, g1, be1);
    ff1_kernel<<<dim3(512, 8), 256, 32768, stream>>>(srcb, ws + 1048576, b1, doutb, qOb);
    ff2_kernel<<<512, 256, 65536, stream>>>(doutb, srcb, qOb, ws + 2097152, b2, g2, be2);
}